// Round 1
// 230.200 us; speedup vs baseline: 1.0373x; 1.0373x over previous
//
#include <hip/hip_runtime.h>

// Problem: MLP_AE_72756745994415
// out[k,i] = V_k(j) with j = i/10 (reference drops the ones digit):
//   j>=1000: x3[4]*AB[j/100]*CD[j%100]
//   j>= 100: x3[3]*AB[j/10]*x3[25+j%10]
//   j>=  10: x3[2]*AB[j]
//   j  1..9: x3[1]*x3[5+j]
//   i == 0 : x3[1]*x3[5]   (per-row column-0 special)
// where AB[m]=x3[5+m/10]*x3[15+m%10], CD[m]=x3[25+m/10]*x3[35+m%10].
//
// R5 (this round): single fused kernel, one block per batch row.
//   Phase 1: MLP (wave-per-32-neurons coalesced GEMV, shfl_xor reduce) + softmax.
//   Phase 2: build VS[10000] value table in LDS (10k cheap evals, not 50k branchy).
//   Phase 3: pure streaming float4 store loop: 1 div + 2 LDS reads + 3 cndmask
//            per 16 B -> store-BW-bound by construction.

#define BATCH 512
#define DIM   512
#define HID   256
#define NCLS  55
#define NOUT  99999
#define LEAK  0.01f

__global__ __launch_bounds__(512) void fused_mlp_expand(
    const float* __restrict__ x,  const float* __restrict__ w2,
    const float* __restrict__ b2, const float* __restrict__ w3,
    const float* __restrict__ b3, float* __restrict__ out) {
    __shared__ float xs[DIM];
    __shared__ float hs[HID];
    __shared__ float x3s[NCLS];
    __shared__ float AB[100];
    __shared__ float CD[100];
    __shared__ float VS[10004];   // +4 pad: stream loop reads VS[j+1] at j=9999
                                  // (value never selected; pad keeps read in-bounds)

    const int tid  = threadIdx.x;
    const int k    = blockIdx.x;
    const int wave = tid >> 6;    // 0..7
    const int lane = tid & 63;

    // ---- stage x row: 512 threads, 512 dims ----
    xs[tid] = x[(size_t)k * DIM + tid];
    __syncthreads();

    // ---- layer 1: wave w computes neurons [32w, 32w+32); coalesced reads ----
    {
        float4 xv0 = ((const float4*)xs)[lane];        // dims [4l, 4l+4)
        float4 xv1 = ((const float4*)xs)[lane + 64];   // dims [256+4l, ...)
        float  acc = 0.f;
#pragma unroll 4
        for (int t = 0; t < 32; ++t) {
            const int n = wave * 32 + t;
            const float4* w2r = (const float4*)(w2 + (size_t)n * DIM);
            float4 a = w2r[lane];        // 1 KB contiguous across the wave
            float4 b = w2r[lane + 64];   // second KB
            float s = a.x * xv0.x + a.y * xv0.y + a.z * xv0.z + a.w * xv0.w
                    + b.x * xv1.x + b.y * xv1.y + b.z * xv1.z + b.w * xv1.w;
#pragma unroll
            for (int off = 1; off < 64; off <<= 1) s += __shfl_xor(s, off, 64);
            if (lane == t) acc = s;      // neuron t's total lands in lane t
        }
        if (lane < 32) {
            float hv = acc + b2[wave * 32 + lane];
            hs[wave * 32 + lane] = (hv >= 0.f) ? hv : LEAK * hv;
        }
    }
    __syncthreads();

    // ---- layer 2: wave w handles outputs o = w, w+8, ...; coalesced ----
    {
        float4 hv = ((const float4*)hs)[lane];   // dims [4l, 4l+4)
        for (int o = wave; o < NCLS; o += 8) {
            const float4* w3r = (const float4*)(w3 + (size_t)o * HID);
            float4 w = w3r[lane];        // 1 KB contiguous
            float s = w.x * hv.x + w.y * hv.y + w.z * hv.z + w.w * hv.w;
#pragma unroll
            for (int off = 1; off < 64; off <<= 1) s += __shfl_xor(s, off, 64);
            if (lane == 0) x3s[o] = s + b3[o];
        }
    }
    __syncthreads();

    // ---- softmax: 6 groups (len 5, then 5x len 10) ----
    if (tid < 6) {
        int off = (tid == 0) ? 0 : 5 + 10 * (tid - 1);
        int len = (tid == 0) ? 5 : 10;
        float m = -1e30f;
        for (int u = 0; u < len; ++u) m = fmaxf(m, x3s[off + u]);
        float s = 0.f;
        for (int u = 0; u < len; ++u) {
            float e = __expf(x3s[off + u] - m);
            x3s[off + u] = e;
            s += e;
        }
        float inv = 1.f / s;
        for (int u = 0; u < len; ++u) x3s[off + u] *= inv;
    }
    __syncthreads();

    // ---- digit-pair product tables ----
    if (tid < 100) {
        int hi = tid / 10, lo = tid % 10;
        AB[tid] = x3s[5 + hi] * x3s[15 + lo];
        CD[tid] = x3s[25 + hi] * x3s[35 + lo];
    }
    __syncthreads();

    // ---- build the full 10000-entry value table (one eval per distinct j) ----
    {
        const float A10 = x3s[0];
        const float L1 = x3s[1], L2 = x3s[2], L3 = x3s[3], L4 = x3s[4];
        for (int j = tid; j < 10000; j += 512) {
            unsigned ju = (unsigned)j;
            float v;
            if (ju >= 1000u)      { unsigned q = ju / 100u; v = L4 * AB[q] * CD[ju - q * 100u]; }
            else if (ju >= 100u)  { unsigned q = ju / 10u;  v = L3 * AB[q] * x3s[25 + (ju - q * 10u)]; }
            else if (ju >= 10u)   { v = L2 * AB[ju]; }
            else                  { v = (ju == 0u) ? A10 : L1 * x3s[5 + ju]; }
            VS[j] = v;
        }
    }
    __syncthreads();

    // ---- streaming expansion: row k, 99999 elements ----
    const float  pz = x3s[1] * x3s[5];            // i==0 special value
    const size_t rb = (size_t)k * NOUT;
    const unsigned h     = (unsigned)((4u - (unsigned)(rb & 3)) & 3u);  // align-up head
    const unsigned ng    = ((unsigned)NOUT - h) >> 2;
    const unsigned tail0 = h + (ng << 2);

    if (tid < (int)h) {                            // e in [0,h), h<=3 -> j==0
        unsigned e = (unsigned)tid;
        out[rb + e] = (e == 0u) ? pz : VS[0];
    }
    if (tid < (int)((unsigned)NOUT - tail0)) {     // up to 3 tail elements -> j==9999
        unsigned e = tail0 + (unsigned)tid;
        out[rb + e] = VS[e / 10u];
    }

    float4* outv = (float4*)(out + rb + h);
    for (unsigned g = tid; g < ng; g += 512) {
        unsigned e   = h + (g << 2);
        unsigned j   = e / 10u;                    // magic-mul
        unsigned rem = e - j * 10u;                // 0..9
        float v0 = VS[j];
        float v1 = VS[j + 1];
        float4 v;
        v.x = (e == 0u)  ? pz : v0;
        v.y = (rem < 9u) ? v0 : v1;
        v.z = (rem < 8u) ? v0 : v1;
        v.w = (rem < 7u) ? v0 : v1;
        outv[g] = v;
    }
}

extern "C" void kernel_launch(void* const* d_in, const int* in_sizes, int n_in,
                              void* d_out, int out_size, void* d_ws, size_t ws_size,
                              hipStream_t stream) {
    const float* x  = (const float*)d_in[0];
    const float* w2 = (const float*)d_in[1];
    const float* b2 = (const float*)d_in[2];
    const float* w3 = (const float*)d_in[3];
    const float* b3 = (const float*)d_in[4];
    float* out = (float*)d_out;

    fused_mlp_expand<<<BATCH, 512, 0, stream>>>(x, w2, b2, w3, b3, out);
}

// Round 2
// 228.207 us; speedup vs baseline: 1.0463x; 1.0087x over previous
//
#include <hip/hip_runtime.h>

// Problem: MLP_AE_72756745994415
// out[k,i] = V_k(j) with j = i/10 (reference drops the ones digit):
//   j>=1000: x3[4]*AB[j/100]*CD[j%100]
//   j>= 100: x3[3]*AB[j/10]*x3[25+j%10]
//   j>=  10: x3[2]*AB[j]
//   j  1..9: x3[1]*x3[5+j]
//   i == 0 : x3[1]*x3[5]   (per-row column-0 special)
//
// R6 (this round): de-hotspot the GEMV.
//   Theory: all 512 blocks read the SAME w2 addresses in lockstep -> L2
//   channel hotspot (~1/16 of L2 BW) -> ~75 us MLP phase. Fix: per-block
//   rotation of row order (k & 31) and column phase (k >> 5). Dot products
//   are order-invariant, so results are identical up to fp reassociation.
//   VS-table build + streaming store loop unchanged from R5.

#define BATCH 512
#define DIM   512
#define HID   256
#define NCLS  55
#define NOUT  99999
#define LEAK  0.01f

__global__ __launch_bounds__(512) void fused_mlp_expand(
    const float* __restrict__ x,  const float* __restrict__ w2,
    const float* __restrict__ b2, const float* __restrict__ w3,
    const float* __restrict__ b3, float* __restrict__ out) {
    __shared__ float xs[DIM];
    __shared__ float hs[HID];
    __shared__ float x3s[NCLS];
    __shared__ float AB[100];
    __shared__ float CD[100];
    __shared__ float VS[10004];   // +4 pad: stream loop reads VS[j+1] at j=9999

    const int tid  = threadIdx.x;
    const int k    = blockIdx.x;
    const int wave = tid >> 6;    // 0..7
    const int lane = tid & 63;

    // Per-block de-hotspot rotations (see header comment).
    const int rot_row = k & 31;             // row-order phase within each wave's 32 rows
    const int cl      = (lane + (k >> 5)) & 63;  // column phase (float4 index 0..63)

    // ---- stage x row: 512 threads, 512 dims ----
    xs[tid] = x[(size_t)k * DIM + tid];
    __syncthreads();

    // ---- layer 1: wave w computes neurons [32w, 32w+32); rotated access ----
    {
        float4 xv0 = ((const float4*)xs)[cl];        // dims [4cl, 4cl+4)
        float4 xv1 = ((const float4*)xs)[cl + 64];   // dims [256+4cl, ...)
        float  acc = 0.f;
#pragma unroll 4
        for (int t = 0; t < 32; ++t) {
            const int te = (t + rot_row) & 31;       // block-rotated row order
            const int n  = wave * 32 + te;
            const float4* w2r = (const float4*)(w2 + (size_t)n * DIM);
            float4 a = w2r[cl];        // contiguous 1 KB across the wave (rotated phase)
            float4 b = w2r[cl + 64];   // second KB
            float s = a.x * xv0.x + a.y * xv0.y + a.z * xv0.z + a.w * xv0.w
                    + b.x * xv1.x + b.y * xv1.y + b.z * xv1.z + b.w * xv1.w;
#pragma unroll
            for (int off = 1; off < 64; off <<= 1) s += __shfl_xor(s, off, 64);
            if (lane == te) acc = s;   // neuron te's total lands in lane te
        }
        if (lane < 32) {
            float hv = acc + b2[wave * 32 + lane];
            hs[wave * 32 + lane] = (hv >= 0.f) ? hv : LEAK * hv;
        }
    }
    __syncthreads();

    // ---- layer 2: wave w handles outputs o = w, w+8, ...; rotated columns ----
    {
        float4 hv = ((const float4*)hs)[cl];   // dims [4cl, 4cl+4)
        for (int o = wave; o < NCLS; o += 8) {
            const float4* w3r = (const float4*)(w3 + (size_t)o * HID);
            float4 w = w3r[cl];        // 1 KB contiguous (rotated phase)
            float s = w.x * hv.x + w.y * hv.y + w.z * hv.z + w.w * hv.w;
#pragma unroll
            for (int off = 1; off < 64; off <<= 1) s += __shfl_xor(s, off, 64);
            if (lane == 0) x3s[o] = s + b3[o];
        }
    }
    __syncthreads();

    // ---- softmax: 6 groups (len 5, then 5x len 10) ----
    if (tid < 6) {
        int off = (tid == 0) ? 0 : 5 + 10 * (tid - 1);
        int len = (tid == 0) ? 5 : 10;
        float m = -1e30f;
        for (int u = 0; u < len; ++u) m = fmaxf(m, x3s[off + u]);
        float s = 0.f;
        for (int u = 0; u < len; ++u) {
            float e = __expf(x3s[off + u] - m);
            x3s[off + u] = e;
            s += e;
        }
        float inv = 1.f / s;
        for (int u = 0; u < len; ++u) x3s[off + u] *= inv;
    }
    __syncthreads();

    // ---- digit-pair product tables ----
    if (tid < 100) {
        int hi = tid / 10, lo = tid % 10;
        AB[tid] = x3s[5 + hi] * x3s[15 + lo];
        CD[tid] = x3s[25 + hi] * x3s[35 + lo];
    }
    __syncthreads();

    // ---- build the full 10000-entry value table (one eval per distinct j) ----
    {
        const float A10 = x3s[0];
        const float L1 = x3s[1], L2 = x3s[2], L3 = x3s[3], L4 = x3s[4];
        for (int j = tid; j < 10000; j += 512) {
            unsigned ju = (unsigned)j;
            float v;
            if (ju >= 1000u)      { unsigned q = ju / 100u; v = L4 * AB[q] * CD[ju - q * 100u]; }
            else if (ju >= 100u)  { unsigned q = ju / 10u;  v = L3 * AB[q] * x3s[25 + (ju - q * 10u)]; }
            else if (ju >= 10u)   { v = L2 * AB[ju]; }
            else                  { v = (ju == 0u) ? A10 : L1 * x3s[5 + ju]; }
            VS[j] = v;
        }
    }
    __syncthreads();

    // ---- streaming expansion: row k, 99999 elements ----
    const float  pz = x3s[1] * x3s[5];            // i==0 special value
    const size_t rb = (size_t)k * NOUT;
    const unsigned h     = (unsigned)((4u - (unsigned)(rb & 3)) & 3u);  // align-up head
    const unsigned ng    = ((unsigned)NOUT - h) >> 2;
    const unsigned tail0 = h + (ng << 2);

    if (tid < (int)h) {                            // e in [0,h), h<=3 -> j==0
        unsigned e = (unsigned)tid;
        out[rb + e] = (e == 0u) ? pz : VS[0];
    }
    if (tid < (int)((unsigned)NOUT - tail0)) {     // up to 3 tail elements -> j==9999
        unsigned e = tail0 + (unsigned)tid;
        out[rb + e] = VS[e / 10u];
    }

    float4* outv = (float4*)(out + rb + h);
    for (unsigned g = tid; g < ng; g += 512) {
        unsigned e   = h + (g << 2);
        unsigned j   = e / 10u;                    // magic-mul
        unsigned rem = e - j * 10u;                // 0..9
        float v0 = VS[j];
        float v1 = VS[j + 1];
        float4 v;
        v.x = (e == 0u)  ? pz : v0;
        v.y = (rem < 9u) ? v0 : v1;
        v.z = (rem < 8u) ? v0 : v1;
        v.w = (rem < 7u) ? v0 : v1;
        outv[g] = v;
    }
}

extern "C" void kernel_launch(void* const* d_in, const int* in_sizes, int n_in,
                              void* d_out, int out_size, void* d_ws, size_t ws_size,
                              hipStream_t stream) {
    const float* x  = (const float*)d_in[0];
    const float* w2 = (const float*)d_in[1];
    const float* b2 = (const float*)d_in[2];
    const float* w3 = (const float*)d_in[3];
    const float* b3 = (const float*)d_in[4];
    float* out = (float*)d_out;

    fused_mlp_expand<<<BATCH, 512, 0, stream>>>(x, w2, b2, w3, b3, out);
}